// Round 5
// baseline (194.106 us; speedup 1.0000x reference)
//
#include <hip/hip_runtime.h>

#define BB 64
#define SS 1024
#define HH 512
#define EE 512
#define VV 32000
#define PP 40

typedef __attribute__((ext_vector_type(8))) __bf16 bf16x8;
typedef __attribute__((ext_vector_type(4))) float f32x4;
typedef __attribute__((ext_vector_type(8))) unsigned short us8_t;
typedef __attribute__((ext_vector_type(4))) unsigned short us4_t;

__device__ inline float fast_tanh(float x) {
    float e = __expf(-2.0f * fabsf(x));
    float t = (1.0f - e) / (1.0f + e);
    return copysignf(t, x);
}
__device__ inline float sigmf(float x) { return 1.0f / (1.0f + __expf(-x)); }

__device__ inline unsigned int cvtpk(float lo, float hi) {
    unsigned int r;
    asm volatile("v_cvt_pk_bf16_f32 %0, %1, %2" : "=v"(r) : "v"(lo), "v"(hi));
    return r;
}
__device__ inline us8_t pack8c(float4 x, float4 y) {
    union { unsigned int u[4]; us8_t v; } r;
    r.u[0] = cvtpk(x.x, x.y); r.u[1] = cvtpk(x.z, x.w);
    r.u[2] = cvtpk(y.x, y.y); r.u[3] = cvtpk(y.z, y.w);
    return r.v;
}

// ---------------------------------------------------------------------------
// k_prep: qs = hidden @ W_s^T (blocks 0..63), W_h f32->bf16 (64..95),
//         gate = sigmoid(pos_onehot @ W_p + b_p) (96..351), zero ctx (352..359)
// ---------------------------------------------------------------------------
__global__ __launch_bounds__(256)
void k_prep(const float* __restrict__ hidden, const float* __restrict__ Ws,
            const float* __restrict__ Wh, const float* __restrict__ pos,
            const float* __restrict__ Wp, const float* __restrict__ bp,
            unsigned short* __restrict__ wh16, float* __restrict__ qs,
            float* __restrict__ gate, float* __restrict__ ctx) {
    int blk = blockIdx.x, t = threadIdx.x;
    if (blk < 64) {
        __shared__ float hb[HH];
        int b = blk;
        for (int i = t; i < HH; i += 256) hb[i] = hidden[b * HH + i];
        __syncthreads();
        for (int n = t; n < HH; n += 256) {
            const float* wr = Ws + (size_t)n * HH;
            float acc = 0.0f;
#pragma unroll 4
            for (int k = 0; k < HH; k += 4) {
                float4 w = *(const float4*)(wr + k);
                acc += w.x * hb[k] + w.y * hb[k + 1] + w.z * hb[k + 2] + w.w * hb[k + 3];
            }
            qs[b * HH + n] = acc;
        }
    } else if (blk < 96) {
        int base = (blk - 64) * 8192 + t * 4;
#pragma unroll
        for (int j = 0; j < 8; ++j) {
            int idx = base + j * 1024;
            float4 x = *(const float4*)(Wh + idx);
            union { unsigned int u[2]; us4_t v; } r;
            r.u[0] = cvtpk(x.x, x.y); r.u[1] = cvtpk(x.z, x.w);
            *(us4_t*)(wh16 + idx) = r.v;
        }
    } else if (blk < 352) {
        int idx = (blk - 96) * 256 + t;  // 0..65535 = b*S+s
        const float* pr = pos + (size_t)idx * PP;
        float acc = bp[0];
#pragma unroll
        for (int j = 0; j < 10; ++j) {
            float4 x = *(const float4*)(pr + j * 4);
            acc += x.x * Wp[j * 4] + x.y * Wp[j * 4 + 1] + x.z * Wp[j * 4 + 2] + x.w * Wp[j * 4 + 3];
        }
        gate[idx] = sigmf(acc);
    } else {
        int idx = (blk - 352) * 256 + t;  // ctx zero
#pragma unroll
        for (int j = 0; j < 16; ++j) ctx[idx * 16 + j] = 0.0f;
    }
}

// ---------------------------------------------------------------------------
// k_scores v4: waves own n; areg FORCED register-resident via waves_per_eu(2,2).
// enc tiles double-buffered in LDS; manual lgkmcnt(0)+s_barrier (vmcnt stays
// outstanding across barriers -> prefetch survives). cvt_pk packed conversion.
// nh==0 blocks side-write bf16 enc for k_context. grid 1024 = nh(2)xb(64)xsc(8).
// LDS slot layout conflict-free both sides:
//   phys16(slot,row) = slot*256B + ((row^slot)&15)*16B, slot = ks*4+lq.
// ---------------------------------------------------------------------------
__global__ __launch_bounds__(512)
__attribute__((amdgpu_waves_per_eu(2, 2)))
void k_scores(const float* __restrict__ enc, const unsigned short* __restrict__ wh16,
              const float* __restrict__ qs, const float* __restrict__ Vw,
              float* __restrict__ part, unsigned short* __restrict__ enc16, int do16) {
    __shared__ unsigned short tile[2][8192];   // 2 x 16KB
    __shared__ float pbuf[8][128];
    int bid = blockIdx.x;
    int nh = bid >> 9, rest = bid & 511;
    int b = rest >> 3, sc = rest & 7;
    int s0 = sc * 128;
    int w = threadIdx.x >> 6, lane = threadIdx.x & 63;
    int l15 = lane & 15, lq = lane >> 4;
    int n0w = nh * 256 + w * 32;

    // A-frags: W_h rows (n), 32 per wave, whole K=512 resident (128 VGPR)
    us8_t areg[2][16];
    const unsigned short* abase = wh16 + (size_t)(n0w + l15) * 512 + lq * 8;
#pragma unroll
    for (int nf = 0; nf < 2; ++nf)
#pragma unroll
        for (int ks = 0; ks < 16; ++ks)
            areg[nf][ks] = *(const us8_t*)(abase + nf * 16 * 512 + ks * 32);

    float qv[2][4], vw[2][4];
#pragma unroll
    for (int nf = 0; nf < 2; ++nf)
#pragma unroll
        for (int r = 0; r < 4; ++r) {
            int n = n0w + nf * 16 + lq * 4 + r;
            qv[nf][r] = qs[b * HH + n];
            vw[nf][r] = Vw[n];
        }

    // staging mapping: thread -> (s-row sr, 16-elem k-chunk seg)
    int sr = threadIdx.x >> 5, seg = threadIdx.x & 31;
    const float* gsrc = enc + ((size_t)(b * SS + s0 + sr)) * HH + seg * 16;
    int slot1 = (seg >> 1) * 4 + (seg & 1) * 2;
    int off1 = slot1 * 128 + ((sr ^ (slot1 & 15)) & 15) * 8;
    int off2 = (slot1 + 1) * 128 + ((sr ^ ((slot1 + 1) & 15)) & 15) * 8;
    bool dow = (do16 != 0) && (nh == 0);
    unsigned short* e16base = enc16 + ((size_t)(b * SS + s0 + sr)) * HH + seg * 16;

    // prologue: stage 0 -> tile0 (+enc16), then issue stage-1 loads
    float4 x0 = *(const float4*)(gsrc);
    float4 x1 = *(const float4*)(gsrc + 4);
    float4 x2 = *(const float4*)(gsrc + 8);
    float4 x3 = *(const float4*)(gsrc + 12);
    {
        us8_t va = pack8c(x0, x1), vb = pack8c(x2, x3);
        *(us8_t*)(tile[0] + off1) = va;
        *(us8_t*)(tile[0] + off2) = vb;
        if (dow) { *(us8_t*)(e16base) = va; *(us8_t*)(e16base + 8) = vb; }
    }
    {
        const float* g = gsrc + (size_t)16 * HH;
        x0 = *(const float4*)(g);
        x1 = *(const float4*)(g + 4);
        x2 = *(const float4*)(g + 8);
        x3 = *(const float4*)(g + 12);
    }
    asm volatile("s_waitcnt lgkmcnt(0)" ::: "memory");
    __builtin_amdgcn_s_barrier();

#pragma unroll
    for (int st = 0; st < 8; ++st) {
        // issue loads for stage st+2 first (stay in flight across the barrier)
        float4 y0, y1, y2, y3;
        if (st < 6) {
            const float* g = gsrc + (size_t)(st + 2) * 16 * HH;
            y0 = *(const float4*)(g);
            y1 = *(const float4*)(g + 4);
            y2 = *(const float4*)(g + 8);
            y3 = *(const float4*)(g + 12);
        }
        // compute on current tile
        const unsigned short* tb = tile[st & 1];
        f32x4 acc0 = {0.f, 0.f, 0.f, 0.f};
        f32x4 acc1 = {0.f, 0.f, 0.f, 0.f};
#pragma unroll
        for (int ks = 0; ks < 16; ++ks) {
            int u = ks * 4 + lq;
            us8_t bf = *(const us8_t*)(tb + u * 128 + ((l15 ^ (u & 15)) & 15) * 8);
            acc0 = __builtin_amdgcn_mfma_f32_16x16x32_bf16(
                __builtin_bit_cast(bf16x8, areg[0][ks]),
                __builtin_bit_cast(bf16x8, bf), acc0, 0, 0, 0);
            acc1 = __builtin_amdgcn_mfma_f32_16x16x32_bf16(
                __builtin_bit_cast(bf16x8, areg[1][ks]),
                __builtin_bit_cast(bf16x8, bf), acc1, 0, 0, 0);
        }
        float p = 0.0f;
#pragma unroll
        for (int r = 0; r < 4; ++r) {
            p += fast_tanh(acc0[r] + qv[0][r]) * vw[0][r];
            p += fast_tanh(acc1[r] + qv[1][r]) * vw[1][r];
        }
        p += __shfl_xor(p, 16, 64);
        p += __shfl_xor(p, 32, 64);
        if (lq == 0) pbuf[w][st * 16 + l15] = p;

        // write next tile from regs loaded one stage ago
        if (st < 7) {
            us8_t va = pack8c(x0, x1), vb = pack8c(x2, x3);
            unsigned short* tn = (unsigned short*)tile[(st + 1) & 1];
            *(us8_t*)(tn + off1) = va;
            *(us8_t*)(tn + off2) = vb;
            if (dow) {
                unsigned short* e = e16base + (size_t)(st + 1) * 16 * HH;
                *(us8_t*)(e) = va;
                *(us8_t*)(e + 8) = vb;
            }
        }
        asm volatile("s_waitcnt lgkmcnt(0)" ::: "memory");
        __builtin_amdgcn_s_barrier();
        if (st < 6) { x0 = y0; x1 = y1; x2 = y2; x3 = y3; }
    }

    if (threadIdx.x < 128) {
        float s = 0.0f;
#pragma unroll
        for (int ww = 0; ww < 8; ++ww) s += pbuf[ww][threadIdx.x];
        part[nh * (BB * SS) + b * SS + s0 + threadIdx.x] = s;
    }
}

// ---------------------------------------------------------------------------
// k_context (softmax fused): redundant row-denominator per chunk block,
// attn slice write, context accumulation (bf16 enc16 path halves HBM).
// grid 1024 = b(64) x chunk(16); 256 threads, thread owns h-pair (2t, 2t+1).
// ---------------------------------------------------------------------------
__global__ __launch_bounds__(256)
void k_context(const float* __restrict__ enc, const unsigned short* __restrict__ enc16,
               int use16, const float* __restrict__ part, const float* __restrict__ gate,
               const unsigned char* __restrict__ mask,
               float* __restrict__ attn, float* __restrict__ ctx) {
    int b = blockIdx.x >> 4, chunk = blockIdx.x & 15;
    int s0 = chunk * 64, t = threadIdx.x;
    int w = t >> 6, ln = t & 63;
    float sum = 0.0f;
#pragma unroll
    for (int j = 0; j < 4; ++j) {
        int s = j * 256 + t;
        float raw = part[b * SS + s] + part[BB * SS + b * SS + s];
        float v = mask[b * SS + s] ? -1e30f : raw * gate[b * SS + s];
        sum += __expf(v);
    }
#pragma unroll
    for (int off = 1; off < 64; off <<= 1) sum += __shfl_xor(sum, off, 64);
    __shared__ float sl[4];
    if (ln == 0) sl[w] = sum;
    __syncthreads();
    float inv = 1.0f / (sl[0] + sl[1] + sl[2] + sl[3]);

    __shared__ float aw[64];
    if (t < 64) {
        int s = s0 + t;
        float raw = part[b * SS + s] + part[BB * SS + b * SS + s];
        float v = mask[b * SS + s] ? -1e30f : raw * gate[b * SS + s];
        float a = __expf(v) * inv;
        aw[t] = a;
        attn[b * SS + s] = a;
    }
    __syncthreads();

    float a0 = 0.f, a1 = 0.f;
    if (use16) {
        const unsigned short* eb = enc16 + ((size_t)(b * SS + s0)) * HH + 2 * t;
#pragma unroll 4
        for (int s = 0; s < 64; ++s) {
            unsigned int u = *(const unsigned int*)(eb + (size_t)s * HH);
            a0 += aw[s] * __uint_as_float(u << 16);
            a1 += aw[s] * __uint_as_float(u & 0xffff0000u);
        }
    } else {
        const float* eb = enc + ((size_t)(b * SS + s0)) * HH + 2 * t;
#pragma unroll 4
        for (int s = 0; s < 64; ++s) {
            float2 u = *(const float2*)(eb + (size_t)s * HH);
            a0 += aw[s] * u.x;
            a1 += aw[s] * u.y;
        }
    }
    atomicAdd(&ctx[b * HH + 2 * t], a0);
    atomicAdd(&ctx[b * HH + 2 * t + 1], a1);
}

// ---------------------------------------------------------------------------
// k_build: lstm_in_bf16 = [emb | ctx], h_bf16
// ---------------------------------------------------------------------------
__global__ __launch_bounds__(256)
void k_build(const int* __restrict__ tok, const float* __restrict__ embt,
             const float* __restrict__ ctx, const float* __restrict__ hidden,
             unsigned short* __restrict__ li16, unsigned short* __restrict__ h16v) {
    int b = blockIdx.x, t = threadIdx.x;
    const float* er = embt + (size_t)tok[b] * EE;
    for (int i = 2 * t; i < HH; i += 512) {
        *(unsigned int*)(li16 + b * 1024 + i) = cvtpk(er[i], er[i + 1]);
        *(unsigned int*)(li16 + b * 1024 + 512 + i) = cvtpk(ctx[b * HH + i], ctx[b * HH + i + 1]);
        *(unsigned int*)(h16v + b * HH + i) = cvtpk(hidden[b * HH + i], hidden[b * HH + i + 1]);
    }
}

// ---------------------------------------------------------------------------
// k_gates: gpart[ksl] = lstm_in @ W_ih^T + h @ W_hh^T  (K-slice partials)
// grid 64 = 16 n-tiles(128) x 4 k-slices(384).
// ---------------------------------------------------------------------------
__global__ __launch_bounds__(256)
void k_gates(const unsigned short* __restrict__ li16, const unsigned short* __restrict__ h16v,
             const float* __restrict__ Wih, const float* __restrict__ Whh,
             float* __restrict__ gpart) {
    int nt = blockIdx.x >> 2, ksl = blockIdx.x & 3;
    int wave = threadIdx.x >> 6, lane = threadIdx.x & 63;
    int l15 = lane & 15, lq = lane >> 4, k0 = lq * 8;
    int n0w = nt * 128 + wave * 32;
    f32x4 acc[4][2];
#pragma unroll
    for (int mf = 0; mf < 4; ++mf)
#pragma unroll
        for (int nf = 0; nf < 2; ++nf) acc[mf][nf] = (f32x4){0.f, 0.f, 0.f, 0.f};

    for (int ks = 0; ks < 12; ++ks) {
        int kg = ksl * 384 + ks * 32;
        us8_t af[4];
        if (kg < 1024) {
#pragma unroll
            for (int mf = 0; mf < 4; ++mf)
                af[mf] = *(const us8_t*)(li16 + (mf * 16 + l15) * 1024 + kg + k0);
        } else {
#pragma unroll
            for (int mf = 0; mf < 4; ++mf)
                af[mf] = *(const us8_t*)(h16v + (mf * 16 + l15) * 512 + (kg - 1024) + k0);
        }
#pragma unroll
        for (int nf = 0; nf < 2; ++nf) {
            int n = n0w + nf * 16 + l15;
            us8_t bu;
            if (kg < 1024) {
                const float* wr = Wih + (size_t)n * 1024 + kg + k0;
                bu = pack8c(*(const float4*)wr, *(const float4*)(wr + 4));
            } else {
                const float* wr = Whh + (size_t)n * 512 + (kg - 1024) + k0;
                bu = pack8c(*(const float4*)wr, *(const float4*)(wr + 4));
            }
#pragma unroll
            for (int mf = 0; mf < 4; ++mf)
                acc[mf][nf] = __builtin_amdgcn_mfma_f32_16x16x32_bf16(
                    __builtin_bit_cast(bf16x8, af[mf]),
                    __builtin_bit_cast(bf16x8, bu), acc[mf][nf], 0, 0, 0);
        }
    }
#pragma unroll
    for (int mf = 0; mf < 4; ++mf)
#pragma unroll
        for (int nf = 0; nf < 2; ++nf)
#pragma unroll
            for (int r = 0; r < 4; ++r) {
                int row = mf * 16 + lq * 4 + r;
                int n = n0w + nf * 16 + l15;
                gpart[ksl * (BB * 2048) + row * 2048 + n] = acc[mf][nf][r];
            }
}

// ---------------------------------------------------------------------------
// k_lstm: sum K-slice partials + biases, pointwise cell update
// ---------------------------------------------------------------------------
__global__ __launch_bounds__(512)
void k_lstm(const float* __restrict__ gpart, const float* __restrict__ bih,
            const float* __restrict__ bhh, const float* __restrict__ cell,
            float* __restrict__ oh, float* __restrict__ oc,
            unsigned short* __restrict__ h116) {
    int b = blockIdx.x, t = threadIdx.x;
    float gi = bih[t] + bhh[t];
    float gf = bih[512 + t] + bhh[512 + t];
    float gg = bih[1024 + t] + bhh[1024 + t];
    float go = bih[1536 + t] + bhh[1536 + t];
#pragma unroll
    for (int ksl = 0; ksl < 4; ++ksl) {
        const float* gp = gpart + ksl * (BB * 2048) + b * 2048;
        gi += gp[t];
        gf += gp[512 + t];
        gg += gp[1024 + t];
        go += gp[1536 + t];
    }
    float c0 = cell[b * HH + t];
    float c1 = sigmf(gf) * c0 + sigmf(gi) * fast_tanh(gg);
    float h1 = sigmf(go) * fast_tanh(c1);
    oh[b * HH + t] = h1;
    oc[b * HH + t] = c1;
    h116[b * HH + t] = (unsigned short)(cvtpk(h1, h1) & 0xffffu);
}

// ---------------------------------------------------------------------------
// k_pred: pred = h1 @ W_out^T + b_out  (M=64, N=32000, K=512)
// ---------------------------------------------------------------------------
__global__ __launch_bounds__(512)
void k_pred(const unsigned short* __restrict__ h116, const float* __restrict__ Wout,
            const float* __restrict__ bout, float* __restrict__ pred) {
    int wave = threadIdx.x >> 6, lane = threadIdx.x & 63;
    int l15 = lane & 15, lq = lane >> 4, k0 = lq * 8;
    int n = blockIdx.x * 128 + wave * 16 + l15;
    f32x4 acc[4];
#pragma unroll
    for (int mf = 0; mf < 4; ++mf) acc[mf] = (f32x4){0.f, 0.f, 0.f, 0.f};
    const float* wr = Wout + (size_t)n * HH;
#pragma unroll 4
    for (int ks = 0; ks < 16; ++ks) {
        float4 x = *(const float4*)(wr + ks * 32 + k0);
        float4 y = *(const float4*)(wr + ks * 32 + k0 + 4);
        us8_t bu = pack8c(x, y);
#pragma unroll
        for (int mf = 0; mf < 4; ++mf) {
            us8_t au = *(const us8_t*)(h116 + (mf * 16 + l15) * 512 + ks * 32 + k0);
            acc[mf] = __builtin_amdgcn_mfma_f32_16x16x32_bf16(
                __builtin_bit_cast(bf16x8, au),
                __builtin_bit_cast(bf16x8, bu), acc[mf], 0, 0, 0);
        }
    }
    float bo = bout[n];
#pragma unroll
    for (int mf = 0; mf < 4; ++mf)
#pragma unroll
        for (int r = 0; r < 4; ++r) {
            int row = mf * 16 + lq * 4 + r;
            pred[(size_t)row * VV + n] = acc[mf][r] + bo;
        }
}

// ---------------------------------------------------------------------------
extern "C" void kernel_launch(void* const* d_in, const int* in_sizes, int n_in,
                              void* d_out, int out_size, void* d_ws, size_t ws_size,
                              hipStream_t stream) {
    const int* tok = (const int*)d_in[0];
    const float* hidden = (const float*)d_in[1];
    const float* cell = (const float*)d_in[2];
    const float* enc = (const float*)d_in[3];
    const float* pos = (const float*)d_in[4];
    const unsigned char* mask = (const unsigned char*)d_in[5];
    const float* embt = (const float*)d_in[6];
    const float* Ws = (const float*)d_in[7];
    const float* Wh = (const float*)d_in[8];
    const float* Vw = (const float*)d_in[9];
    const float* Wp = (const float*)d_in[10];
    const float* bp = (const float*)d_in[11];
    const float* Wih = (const float*)d_in[12];
    const float* Whh = (const float*)d_in[13];
    const float* bih = (const float*)d_in[14];
    const float* bhh = (const float*)d_in[15];
    const float* Wout = (const float*)d_in[16];
    const float* bout = (const float*)d_in[17];

    float* out = (float*)d_out;
    float* pred = out;                  // 64*32000
    float* out_h = out + 2048000;       // 64*512
    float* out_c = out + 2080768;       // 64*512
    float* attn = out + 2113536;        // 64*1024

    char* wsb = (char*)d_ws;
    unsigned short* wh16 = (unsigned short*)(wsb);                 // 512KB
    float* qs = (float*)(wsb + (512 << 10));                       // 128KB
    float* gate = (float*)(wsb + (640 << 10));                     // 256KB
    float* part = (float*)(wsb + (896 << 10));                     // 512KB
    float* ctx = (float*)(wsb + (1408 << 10));                     // 128KB
    unsigned short* li16 = (unsigned short*)(wsb + (1536 << 10));  // 128KB
    unsigned short* h16v = (unsigned short*)(wsb + (1664 << 10));  // 64KB
    float* gpart = (float*)(wsb + (1728 << 10));                   // 2MB
    unsigned short* h116 = (unsigned short*)(wsb + (3776 << 10));  // 64KB
    size_t e16off = (size_t)(3840) << 10;
    size_t e16need = e16off + (size_t)BB * SS * HH * 2;            // +64MB
    int use16 = (ws_size >= e16need) ? 1 : 0;
    unsigned short* enc16 = use16 ? (unsigned short*)(wsb + e16off)
                                  : (unsigned short*)wsb;  // dummy, unused

    hipLaunchKernelGGL(k_prep, dim3(360), dim3(256), 0, stream,
                       hidden, Ws, Wh, pos, Wp, bp, wh16, qs, gate, ctx);
    hipLaunchKernelGGL(k_scores, dim3(1024), dim3(512), 0, stream,
                       enc, wh16, qs, Vw, part, enc16, use16);
    hipLaunchKernelGGL(k_context, dim3(1024), dim3(256), 0, stream,
                       enc, enc16, use16, part, gate, mask, attn, ctx);
    hipLaunchKernelGGL(k_build, dim3(64), dim3(256), 0, stream,
                       tok, embt, ctx, hidden, li16, h16v);
    hipLaunchKernelGGL(k_gates, dim3(64), dim3(256), 0, stream, li16, h16v, Wih, Whh, gpart);
    hipLaunchKernelGGL(k_lstm, dim3(64), dim3(512), 0, stream,
                       gpart, bih, bhh, cell, out_h, out_c, h116);
    hipLaunchKernelGGL(k_pred, dim3(250), dim3(512), 0, stream, h116, Wout, bout, pred);
}

// Round 6
// 190.886 us; speedup vs baseline: 1.0169x; 1.0169x over previous
//
#include <hip/hip_runtime.h>

#define BB 64
#define SS 1024
#define HH 512
#define EE 512
#define VV 32000
#define PP 40

typedef __attribute__((ext_vector_type(8))) __bf16 bf16x8;
typedef __attribute__((ext_vector_type(4))) float f32x4;
typedef __attribute__((ext_vector_type(8))) unsigned short us8_t;
typedef __attribute__((ext_vector_type(4))) unsigned short us4_t;

__device__ inline float fast_tanh(float x) {
    float e = __expf(-2.0f * fabsf(x));
    float t = (1.0f - e) / (1.0f + e);
    return copysignf(t, x);
}
__device__ inline float sigmf(float x) { return 1.0f / (1.0f + __expf(-x)); }

__device__ inline unsigned int cvtpk(float lo, float hi) {
    unsigned int r;
    asm volatile("v_cvt_pk_bf16_f32 %0, %1, %2" : "=v"(r) : "v"(lo), "v"(hi));
    return r;
}
__device__ inline us8_t pack8c(float4 x, float4 y) {
    union { unsigned int u[4]; us8_t v; } r;
    r.u[0] = cvtpk(x.x, x.y); r.u[1] = cvtpk(x.z, x.w);
    r.u[2] = cvtpk(y.x, y.y); r.u[3] = cvtpk(y.z, y.w);
    return r.v;
}

// ---------------------------------------------------------------------------
// k_prep: qs = hidden @ W_s^T (blocks 0..63), W_h f32->bf16 (64..95),
//         gate = sigmoid(pos_onehot @ W_p + b_p) (96..351), zero ctx (352..359)
// ---------------------------------------------------------------------------
__global__ __launch_bounds__(256)
void k_prep(const float* __restrict__ hidden, const float* __restrict__ Ws,
            const float* __restrict__ Wh, const float* __restrict__ pos,
            const float* __restrict__ Wp, const float* __restrict__ bp,
            unsigned short* __restrict__ wh16, float* __restrict__ qs,
            float* __restrict__ gate, float* __restrict__ ctx) {
    int blk = blockIdx.x, t = threadIdx.x;
    if (blk < 64) {
        __shared__ float hb[HH];
        int b = blk;
        for (int i = t; i < HH; i += 256) hb[i] = hidden[b * HH + i];
        __syncthreads();
        for (int n = t; n < HH; n += 256) {
            const float* wr = Ws + (size_t)n * HH;
            float acc = 0.0f;
#pragma unroll 4
            for (int k = 0; k < HH; k += 4) {
                float4 w = *(const float4*)(wr + k);
                acc += w.x * hb[k] + w.y * hb[k + 1] + w.z * hb[k + 2] + w.w * hb[k + 3];
            }
            qs[b * HH + n] = acc;
        }
    } else if (blk < 96) {
        int base = (blk - 64) * 8192 + t * 4;
#pragma unroll
        for (int j = 0; j < 8; ++j) {
            int idx = base + j * 1024;
            float4 x = *(const float4*)(Wh + idx);
            union { unsigned int u[2]; us4_t v; } r;
            r.u[0] = cvtpk(x.x, x.y); r.u[1] = cvtpk(x.z, x.w);
            *(us4_t*)(wh16 + idx) = r.v;
        }
    } else if (blk < 352) {
        int idx = (blk - 96) * 256 + t;  // 0..65535 = b*S+s
        const float* pr = pos + (size_t)idx * PP;
        float acc = bp[0];
#pragma unroll
        for (int j = 0; j < 10; ++j) {
            float4 x = *(const float4*)(pr + j * 4);
            acc += x.x * Wp[j * 4] + x.y * Wp[j * 4 + 1] + x.z * Wp[j * 4 + 2] + x.w * Wp[j * 4 + 3];
        }
        gate[idx] = sigmf(acc);
    } else {
        int idx = (blk - 352) * 256 + t;  // ctx zero
#pragma unroll
        for (int j = 0; j < 16; ++j) ctx[idx * 16 + j] = 0.0f;
    }
}

// ---------------------------------------------------------------------------
// k_scores v5: waves own n; A-frags PINNED in registers via asm "+v" (defeats
// rematerialization of invariant loads across barriers). enc tiles
// double-buffered in LDS; lgkmcnt(0)+raw s_barrier keeps vmem prefetch in
// flight across barriers. grid 1024 = nh(2) x b(64) x sc(8); 8 waves x 32 n.
// LDS slot layout conflict-free both sides:
//   phys16(slot,row) = slot*256B + ((row^slot)&15)*16B, slot = ks*4+lq.
// ---------------------------------------------------------------------------
__global__ __launch_bounds__(512)
__attribute__((amdgpu_waves_per_eu(2, 2)))
void k_scores(const float* __restrict__ enc, const unsigned short* __restrict__ wh16,
              const float* __restrict__ qs, const float* __restrict__ Vw,
              float* __restrict__ part) {
    __shared__ unsigned short tile[2][8192];   // 2 x 16KB
    __shared__ float pbuf[8][128];
    int bid = blockIdx.x;
    int nh = bid >> 9, rest = bid & 511;
    int b = rest >> 3, sc = rest & 7;
    int s0 = sc * 128;
    int w = threadIdx.x >> 6, lane = threadIdx.x & 63;
    int l15 = lane & 15, lq = lane >> 4;
    int n0w = nh * 256 + w * 32;

    // A-frags: W_h rows (n), 32 per wave, whole K=512 resident (128 VGPR).
    // asm "+v" pin makes each value opaque -> no rematerialization.
    us8_t areg[2][16];
    const unsigned short* abase = wh16 + (size_t)(n0w + l15) * 512 + lq * 8;
#pragma unroll
    for (int nf = 0; nf < 2; ++nf)
#pragma unroll
        for (int ks = 0; ks < 16; ++ks) {
            areg[nf][ks] = *(const us8_t*)(abase + nf * 16 * 512 + ks * 32);
            asm volatile("" : "+v"(areg[nf][ks]));
        }

    float qv[2][4], vw[2][4];
#pragma unroll
    for (int nf = 0; nf < 2; ++nf)
#pragma unroll
        for (int r = 0; r < 4; ++r) {
            int n = n0w + nf * 16 + lq * 4 + r;
            qv[nf][r] = qs[b * HH + n];
            vw[nf][r] = Vw[n];
        }

    // staging mapping: thread -> (s-row sr, 16-elem k-chunk seg)
    int sr = threadIdx.x >> 5, seg = threadIdx.x & 31;
    const float* gsrc = enc + ((size_t)(b * SS + s0 + sr)) * HH + seg * 16;
    int slot1 = (seg >> 1) * 4 + (seg & 1) * 2;
    int off1 = slot1 * 128 + ((sr ^ (slot1 & 15)) & 15) * 8;
    int off2 = (slot1 + 1) * 128 + ((sr ^ ((slot1 + 1) & 15)) & 15) * 8;

    // prologue: stage 0 -> tile0, then issue stage-1 loads
    float4 x0 = *(const float4*)(gsrc);
    float4 x1 = *(const float4*)(gsrc + 4);
    float4 x2 = *(const float4*)(gsrc + 8);
    float4 x3 = *(const float4*)(gsrc + 12);
    *(us8_t*)(tile[0] + off1) = pack8c(x0, x1);
    *(us8_t*)(tile[0] + off2) = pack8c(x2, x3);
    {
        const float* g = gsrc + (size_t)16 * HH;
        x0 = *(const float4*)(g);
        x1 = *(const float4*)(g + 4);
        x2 = *(const float4*)(g + 8);
        x3 = *(const float4*)(g + 12);
    }
    asm volatile("s_waitcnt lgkmcnt(0)" ::: "memory");
    __builtin_amdgcn_s_barrier();

#pragma unroll
    for (int st = 0; st < 8; ++st) {
        // issue loads for stage st+2 first (stay in flight across the barrier)
        float4 y0, y1, y2, y3;
        if (st < 6) {
            const float* g = gsrc + (size_t)(st + 2) * 16 * HH;
            y0 = *(const float4*)(g);
            y1 = *(const float4*)(g + 4);
            y2 = *(const float4*)(g + 8);
            y3 = *(const float4*)(g + 12);
        }
        // compute on current tile
        const unsigned short* tb = tile[st & 1];
        f32x4 acc0 = {0.f, 0.f, 0.f, 0.f};
        f32x4 acc1 = {0.f, 0.f, 0.f, 0.f};
#pragma unroll
        for (int ks = 0; ks < 16; ++ks) {
            int u = ks * 4 + lq;
            us8_t bf = *(const us8_t*)(tb + u * 128 + ((l15 ^ (u & 15)) & 15) * 8);
            acc0 = __builtin_amdgcn_mfma_f32_16x16x32_bf16(
                __builtin_bit_cast(bf16x8, areg[0][ks]),
                __builtin_bit_cast(bf16x8, bf), acc0, 0, 0, 0);
            acc1 = __builtin_amdgcn_mfma_f32_16x16x32_bf16(
                __builtin_bit_cast(bf16x8, areg[1][ks]),
                __builtin_bit_cast(bf16x8, bf), acc1, 0, 0, 0);
        }
        float p = 0.0f;
#pragma unroll
        for (int r = 0; r < 4; ++r) {
            p += fast_tanh(acc0[r] + qv[0][r]) * vw[0][r];
            p += fast_tanh(acc1[r] + qv[1][r]) * vw[1][r];
        }
        p += __shfl_xor(p, 16, 64);
        p += __shfl_xor(p, 32, 64);
        if (lq == 0) pbuf[w][st * 16 + l15] = p;

        // write next tile from regs loaded one stage ago
        if (st < 7) {
            unsigned short* tn = (unsigned short*)tile[(st + 1) & 1];
            *(us8_t*)(tn + off1) = pack8c(x0, x1);
            *(us8_t*)(tn + off2) = pack8c(x2, x3);
        }
        asm volatile("s_waitcnt lgkmcnt(0)" ::: "memory");
        __builtin_amdgcn_s_barrier();
        if (st < 6) { x0 = y0; x1 = y1; x2 = y2; x3 = y3; }
    }

    if (threadIdx.x < 128) {
        float s = 0.0f;
#pragma unroll
        for (int ww = 0; ww < 8; ++ww) s += pbuf[ww][threadIdx.x];
        part[nh * (BB * SS) + b * SS + s0 + threadIdx.x] = s;
    }
}

// ---------------------------------------------------------------------------
// k_context (softmax fused): redundant row-denominator per chunk block,
// attn slice write, context accumulation. grid 1024 = b(64) x chunk(16);
// 256 threads, thread owns h-pair (2t, 2t+1).
// ---------------------------------------------------------------------------
__global__ __launch_bounds__(256)
void k_context(const float* __restrict__ enc, const float* __restrict__ part,
               const float* __restrict__ gate, const unsigned char* __restrict__ mask,
               float* __restrict__ attn, float* __restrict__ ctx) {
    int b = blockIdx.x >> 4, chunk = blockIdx.x & 15;
    int s0 = chunk * 64, t = threadIdx.x;
    int w = t >> 6, ln = t & 63;
    float sum = 0.0f;
#pragma unroll
    for (int j = 0; j < 4; ++j) {
        int s = j * 256 + t;
        float raw = part[b * SS + s] + part[BB * SS + b * SS + s];
        float v = mask[b * SS + s] ? -1e30f : raw * gate[b * SS + s];
        sum += __expf(v);
    }
#pragma unroll
    for (int off = 1; off < 64; off <<= 1) sum += __shfl_xor(sum, off, 64);
    __shared__ float sl[4];
    if (ln == 0) sl[w] = sum;
    __syncthreads();
    float inv = 1.0f / (sl[0] + sl[1] + sl[2] + sl[3]);

    __shared__ float aw[64];
    if (t < 64) {
        int s = s0 + t;
        float raw = part[b * SS + s] + part[BB * SS + b * SS + s];
        float v = mask[b * SS + s] ? -1e30f : raw * gate[b * SS + s];
        float a = __expf(v) * inv;
        aw[t] = a;
        attn[b * SS + s] = a;
    }
    __syncthreads();

    const float* eb = enc + ((size_t)(b * SS + s0)) * HH + 2 * t;
    float a0 = 0.f, a1 = 0.f;
#pragma unroll 4
    for (int s = 0; s < 64; ++s) {
        float2 u = *(const float2*)(eb + (size_t)s * HH);
        a0 += aw[s] * u.x;
        a1 += aw[s] * u.y;
    }
    atomicAdd(&ctx[b * HH + 2 * t], a0);
    atomicAdd(&ctx[b * HH + 2 * t + 1], a1);
}

// ---------------------------------------------------------------------------
// k_build: lstm_in_bf16 = [emb | ctx], h_bf16
// ---------------------------------------------------------------------------
__global__ __launch_bounds__(256)
void k_build(const int* __restrict__ tok, const float* __restrict__ embt,
             const float* __restrict__ ctx, const float* __restrict__ hidden,
             unsigned short* __restrict__ li16, unsigned short* __restrict__ h16v) {
    int b = blockIdx.x, t = threadIdx.x;
    const float* er = embt + (size_t)tok[b] * EE;
    for (int i = 2 * t; i < HH; i += 512) {
        *(unsigned int*)(li16 + b * 1024 + i) = cvtpk(er[i], er[i + 1]);
        *(unsigned int*)(li16 + b * 1024 + 512 + i) = cvtpk(ctx[b * HH + i], ctx[b * HH + i + 1]);
        *(unsigned int*)(h16v + b * HH + i) = cvtpk(hidden[b * HH + i], hidden[b * HH + i + 1]);
    }
}

// ---------------------------------------------------------------------------
// k_gates: gpart[ksl] = lstm_in @ W_ih^T + h @ W_hh^T  (K-slice partials)
// grid 64 = 16 n-tiles(128) x 4 k-slices(384).
// ---------------------------------------------------------------------------
__global__ __launch_bounds__(256)
void k_gates(const unsigned short* __restrict__ li16, const unsigned short* __restrict__ h16v,
             const float* __restrict__ Wih, const float* __restrict__ Whh,
             float* __restrict__ gpart) {
    int nt = blockIdx.x >> 2, ksl = blockIdx.x & 3;
    int wave = threadIdx.x >> 6, lane = threadIdx.x & 63;
    int l15 = lane & 15, lq = lane >> 4, k0 = lq * 8;
    int n0w = nt * 128 + wave * 32;
    f32x4 acc[4][2];
#pragma unroll
    for (int mf = 0; mf < 4; ++mf)
#pragma unroll
        for (int nf = 0; nf < 2; ++nf) acc[mf][nf] = (f32x4){0.f, 0.f, 0.f, 0.f};

    for (int ks = 0; ks < 12; ++ks) {
        int kg = ksl * 384 + ks * 32;
        us8_t af[4];
        if (kg < 1024) {
#pragma unroll
            for (int mf = 0; mf < 4; ++mf)
                af[mf] = *(const us8_t*)(li16 + (mf * 16 + l15) * 1024 + kg + k0);
        } else {
#pragma unroll
            for (int mf = 0; mf < 4; ++mf)
                af[mf] = *(const us8_t*)(h16v + (mf * 16 + l15) * 512 + (kg - 1024) + k0);
        }
#pragma unroll
        for (int nf = 0; nf < 2; ++nf) {
            int n = n0w + nf * 16 + l15;
            us8_t bu;
            if (kg < 1024) {
                const float* wr = Wih + (size_t)n * 1024 + kg + k0;
                bu = pack8c(*(const float4*)wr, *(const float4*)(wr + 4));
            } else {
                const float* wr = Whh + (size_t)n * 512 + (kg - 1024) + k0;
                bu = pack8c(*(const float4*)wr, *(const float4*)(wr + 4));
            }
#pragma unroll
            for (int mf = 0; mf < 4; ++mf)
                acc[mf][nf] = __builtin_amdgcn_mfma_f32_16x16x32_bf16(
                    __builtin_bit_cast(bf16x8, af[mf]),
                    __builtin_bit_cast(bf16x8, bu), acc[mf][nf], 0, 0, 0);
        }
    }
#pragma unroll
    for (int mf = 0; mf < 4; ++mf)
#pragma unroll
        for (int nf = 0; nf < 2; ++nf)
#pragma unroll
            for (int r = 0; r < 4; ++r) {
                int row = mf * 16 + lq * 4 + r;
                int n = n0w + nf * 16 + l15;
                gpart[ksl * (BB * 2048) + row * 2048 + n] = acc[mf][nf][r];
            }
}

// ---------------------------------------------------------------------------
// k_lstm: sum K-slice partials + biases, pointwise cell update
// ---------------------------------------------------------------------------
__global__ __launch_bounds__(512)
void k_lstm(const float* __restrict__ gpart, const float* __restrict__ bih,
            const float* __restrict__ bhh, const float* __restrict__ cell,
            float* __restrict__ oh, float* __restrict__ oc,
            unsigned short* __restrict__ h116) {
    int b = blockIdx.x, t = threadIdx.x;
    float gi = bih[t] + bhh[t];
    float gf = bih[512 + t] + bhh[512 + t];
    float gg = bih[1024 + t] + bhh[1024 + t];
    float go = bih[1536 + t] + bhh[1536 + t];
#pragma unroll
    for (int ksl = 0; ksl < 4; ++ksl) {
        const float* gp = gpart + ksl * (BB * 2048) + b * 2048;
        gi += gp[t];
        gf += gp[512 + t];
        gg += gp[1024 + t];
        go += gp[1536 + t];
    }
    float c0 = cell[b * HH + t];
    float c1 = sigmf(gf) * c0 + sigmf(gi) * fast_tanh(gg);
    float h1 = sigmf(go) * fast_tanh(c1);
    oh[b * HH + t] = h1;
    oc[b * HH + t] = c1;
    h116[b * HH + t] = (unsigned short)(cvtpk(h1, h1) & 0xffffu);
}

// ---------------------------------------------------------------------------
// k_pred: pred = h1 @ W_out^T + b_out  (M=64, N=32000, K=512)
// ---------------------------------------------------------------------------
__global__ __launch_bounds__(512)
void k_pred(const unsigned short* __restrict__ h116, const float* __restrict__ Wout,
            const float* __restrict__ bout, float* __restrict__ pred) {
    int wave = threadIdx.x >> 6, lane = threadIdx.x & 63;
    int l15 = lane & 15, lq = lane >> 4, k0 = lq * 8;
    int n = blockIdx.x * 128 + wave * 16 + l15;
    f32x4 acc[4];
#pragma unroll
    for (int mf = 0; mf < 4; ++mf) acc[mf] = (f32x4){0.f, 0.f, 0.f, 0.f};
    const float* wr = Wout + (size_t)n * HH;
#pragma unroll 4
    for (int ks = 0; ks < 16; ++ks) {
        float4 x = *(const float4*)(wr + ks * 32 + k0);
        float4 y = *(const float4*)(wr + ks * 32 + k0 + 4);
        us8_t bu = pack8c(x, y);
#pragma unroll
        for (int mf = 0; mf < 4; ++mf) {
            us8_t au = *(const us8_t*)(h116 + (mf * 16 + l15) * 512 + ks * 32 + k0);
            acc[mf] = __builtin_amdgcn_mfma_f32_16x16x32_bf16(
                __builtin_bit_cast(bf16x8, au),
                __builtin_bit_cast(bf16x8, bu), acc[mf], 0, 0, 0);
        }
    }
    float bo = bout[n];
#pragma unroll
    for (int mf = 0; mf < 4; ++mf)
#pragma unroll
        for (int r = 0; r < 4; ++r) {
            int row = mf * 16 + lq * 4 + r;
            pred[(size_t)row * VV + n] = acc[mf][r] + bo;
        }
}

// ---------------------------------------------------------------------------
extern "C" void kernel_launch(void* const* d_in, const int* in_sizes, int n_in,
                              void* d_out, int out_size, void* d_ws, size_t ws_size,
                              hipStream_t stream) {
    const int* tok = (const int*)d_in[0];
    const float* hidden = (const float*)d_in[1];
    const float* cell = (const float*)d_in[2];
    const float* enc = (const float*)d_in[3];
    const float* pos = (const float*)d_in[4];
    const unsigned char* mask = (const unsigned char*)d_in[5];
    const float* embt = (const float*)d_in[6];
    const float* Ws = (const float*)d_in[7];
    const float* Wh = (const float*)d_in[8];
    const float* Vw = (const float*)d_in[9];
    const float* Wp = (const float*)d_in[10];
    const float* bp = (const float*)d_in[11];
    const float* Wih = (const float*)d_in[12];
    const float* Whh = (const float*)d_in[13];
    const float* bih = (const float*)d_in[14];
    const float* bhh = (const float*)d_in[15];
    const float* Wout = (const float*)d_in[16];
    const float* bout = (const float*)d_in[17];

    float* out = (float*)d_out;
    float* pred = out;                  // 64*32000
    float* out_h = out + 2048000;       // 64*512
    float* out_c = out + 2080768;       // 64*512
    float* attn = out + 2113536;        // 64*1024

    char* wsb = (char*)d_ws;
    unsigned short* wh16 = (unsigned short*)(wsb);                 // 512KB
    float* qs = (float*)(wsb + (512 << 10));                       // 128KB
    float* gate = (float*)(wsb + (640 << 10));                     // 256KB
    float* part = (float*)(wsb + (896 << 10));                     // 512KB
    float* ctx = (float*)(wsb + (1408 << 10));                     // 128KB
    unsigned short* li16 = (unsigned short*)(wsb + (1536 << 10));  // 128KB
    unsigned short* h16v = (unsigned short*)(wsb + (1664 << 10));  // 64KB
    float* gpart = (float*)(wsb + (1728 << 10));                   // 2MB
    unsigned short* h116 = (unsigned short*)(wsb + (3776 << 10));  // 64KB

    hipLaunchKernelGGL(k_prep, dim3(360), dim3(256), 0, stream,
                       hidden, Ws, Wh, pos, Wp, bp, wh16, qs, gate, ctx);
    hipLaunchKernelGGL(k_scores, dim3(1024), dim3(512), 0, stream,
                       enc, wh16, qs, Vw, part);
    hipLaunchKernelGGL(k_context, dim3(1024), dim3(256), 0, stream,
                       enc, part, gate, mask, attn, ctx);
    hipLaunchKernelGGL(k_build, dim3(64), dim3(256), 0, stream,
                       tok, embt, ctx, hidden, li16, h16v);
    hipLaunchKernelGGL(k_gates, dim3(64), dim3(256), 0, stream, li16, h16v, Wih, Whh, gpart);
    hipLaunchKernelGGL(k_lstm, dim3(64), dim3(512), 0, stream,
                       gpart, bih, bhh, cell, out_h, out_c, h116);
    hipLaunchKernelGGL(k_pred, dim3(250), dim3(512), 0, stream, h116, Wout, bout, pred);
}

// Round 7
// 175.752 us; speedup vs baseline: 1.1044x; 1.0861x over previous
//
#include <hip/hip_runtime.h>

#define BB 64
#define SS 1024
#define HH 512
#define EE 512
#define VV 32000
#define PP 40

typedef __attribute__((ext_vector_type(8))) __bf16 bf16x8;
typedef __attribute__((ext_vector_type(4))) float f32x4;
typedef __attribute__((ext_vector_type(8))) unsigned short us8_t;
typedef __attribute__((ext_vector_type(4))) unsigned short us4_t;

__device__ inline float fast_tanh(float x) {
    float e = __expf(-2.0f * fabsf(x));
    float t = (1.0f - e) / (1.0f + e);
    return copysignf(t, x);
}
__device__ inline float sigmf(float x) { return 1.0f / (1.0f + __expf(-x)); }

__device__ inline unsigned int cvtpk(float lo, float hi) {
    unsigned int r;
    asm volatile("v_cvt_pk_bf16_f32 %0, %1, %2" : "=v"(r) : "v"(lo), "v"(hi));
    return r;
}
__device__ inline us8_t pack8c(float4 x, float4 y) {
    union { unsigned int u[4]; us8_t v; } r;
    r.u[0] = cvtpk(x.x, x.y); r.u[1] = cvtpk(x.z, x.w);
    r.u[2] = cvtpk(y.x, y.y); r.u[3] = cvtpk(y.z, y.w);
    return r.v;
}

// ---------------------------------------------------------------------------
// k_prep: qs = hidden @ W_s^T (blocks 0..63), W_h f32->bf16 (64..95),
//         gate = sigmoid(pos_onehot @ W_p + b_p) (96..351), zero ctx (352..359)
// ---------------------------------------------------------------------------
__global__ __launch_bounds__(256)
void k_prep(const float* __restrict__ hidden, const float* __restrict__ Ws,
            const float* __restrict__ Wh, const float* __restrict__ pos,
            const float* __restrict__ Wp, const float* __restrict__ bp,
            unsigned short* __restrict__ wh16, float* __restrict__ qs,
            float* __restrict__ gate, float* __restrict__ ctx) {
    int blk = blockIdx.x, t = threadIdx.x;
    if (blk < 64) {
        __shared__ float hb[HH];
        int b = blk;
        for (int i = t; i < HH; i += 256) hb[i] = hidden[b * HH + i];
        __syncthreads();
        for (int n = t; n < HH; n += 256) {
            const float* wr = Ws + (size_t)n * HH;
            float acc = 0.0f;
#pragma unroll 4
            for (int k = 0; k < HH; k += 4) {
                float4 w = *(const float4*)(wr + k);
                acc += w.x * hb[k] + w.y * hb[k + 1] + w.z * hb[k + 2] + w.w * hb[k + 3];
            }
            qs[b * HH + n] = acc;
        }
    } else if (blk < 96) {
        int base = (blk - 64) * 8192 + t * 4;
#pragma unroll
        for (int j = 0; j < 8; ++j) {
            int idx = base + j * 1024;
            float4 x = *(const float4*)(Wh + idx);
            union { unsigned int u[2]; us4_t v; } r;
            r.u[0] = cvtpk(x.x, x.y); r.u[1] = cvtpk(x.z, x.w);
            *(us4_t*)(wh16 + idx) = r.v;
        }
    } else if (blk < 352) {
        int idx = (blk - 96) * 256 + t;  // 0..65535 = b*S+s
        const float* pr = pos + (size_t)idx * PP;
        float acc = bp[0];
#pragma unroll
        for (int j = 0; j < 10; ++j) {
            float4 x = *(const float4*)(pr + j * 4);
            acc += x.x * Wp[j * 4] + x.y * Wp[j * 4 + 1] + x.z * Wp[j * 4 + 2] + x.w * Wp[j * 4 + 3];
        }
        gate[idx] = sigmf(acc);
    } else {
        int idx = (blk - 352) * 256 + t;  // ctx zero
#pragma unroll
        for (int j = 0; j < 16; ++j) ctx[idx * 16 + j] = 0.0f;
    }
}

// ---------------------------------------------------------------------------
// k_scores v6: classic LDS-tiled GEMM. C(s,n) = enc @ Wh^T, block 128s x 256n,
// 16 K-steps of BK=32. 8 waves (2m x 4n), wave tile 64x64: 4 A-frags + 4
// B-frags (8 ds_read_b128) -> 16 MFMA per step. LDS rows padded to 80B
// (5 x 16B -> bank-group (5r+lq)&7 is a permutation: conflict-free).
// Epilogue fuses tanh*Vw + n-reduction. grid 1024 = nh(2) x b(64) x sc(8);
// nh-siblings (bid +/-512, same XCD) dedup enc in L2/L3.
// Raw s_barrier + lgkmcnt keeps global prefetch in flight across barriers.
// ---------------------------------------------------------------------------
__global__ __launch_bounds__(512)
void k_scores(const float* __restrict__ enc, const unsigned short* __restrict__ wh16,
              const float* __restrict__ qs, const float* __restrict__ Vw,
              float* __restrict__ part) {
    __shared__ unsigned short As[128 * 40];   // 10.24 KB (stride 40 ushorts = 80B)
    __shared__ unsigned short Bs[256 * 40];   // 20.48 KB
    __shared__ float pbuf[4][128];
    int bid = blockIdx.x;
    int nh = bid >> 9, rest = bid & 511;
    int b = rest >> 3, sc = rest & 7;
    int s0 = sc * 128, n0 = nh * 256;
    int tid = threadIdx.x;
    int w = tid >> 6, lane = tid & 63;
    int wm = w >> 2, wn = w & 3;
    int l15 = lane & 15, lq = lane >> 4;

    float qv[4], vw[4];
#pragma unroll
    for (int nf = 0; nf < 4; ++nf) {
        int n = n0 + wn * 64 + nf * 16 + l15;
        qv[nf] = qs[b * HH + n];
        vw[nf] = Vw[n];
    }

    // staging mapping: A: 4 thr/row x 8 f32; B: 2 thr/row x 16 bf16
    int ar = tid >> 2, akseg = tid & 3;
    const float* aSrc = enc + ((size_t)(b * SS + s0 + ar)) * HH + akseg * 8;
    int br = tid >> 1, bkseg = tid & 1;
    const unsigned short* bSrc = wh16 + (size_t)(n0 + br) * HH + bkseg * 16;
    int aOff = ar * 40 + akseg * 8;
    int bOff = br * 40 + bkseg * 16;

    int aRd[4], bRd[4];
#pragma unroll
    for (int mf = 0; mf < 4; ++mf) aRd[mf] = (wm * 64 + mf * 16 + l15) * 40 + lq * 8;
#pragma unroll
    for (int nf = 0; nf < 4; ++nf) bRd[nf] = (wn * 64 + nf * 16 + l15) * 40 + lq * 8;

    f32x4 acc[4][4];
#pragma unroll
    for (int mf = 0; mf < 4; ++mf)
#pragma unroll
        for (int nf = 0; nf < 4; ++nf) acc[mf][nf] = (f32x4){0.f, 0.f, 0.f, 0.f};

    // prologue: step 0 straight to LDS, issue step-1 loads
    {
        float4 a0 = *(const float4*)(aSrc);
        float4 a1 = *(const float4*)(aSrc + 4);
        us8_t b0 = *(const us8_t*)(bSrc);
        us8_t b1 = *(const us8_t*)(bSrc + 8);
        *(us8_t*)(As + aOff) = pack8c(a0, a1);
        *(us8_t*)(Bs + bOff) = b0;
        *(us8_t*)(Bs + bOff + 8) = b1;
    }
    float4 xa0 = *(const float4*)(aSrc + 32);
    float4 xa1 = *(const float4*)(aSrc + 36);
    us8_t xb0 = *(const us8_t*)(bSrc + 32);
    us8_t xb1 = *(const us8_t*)(bSrc + 40);
    asm volatile("s_waitcnt lgkmcnt(0)" ::: "memory");
    __builtin_amdgcn_s_barrier();

#pragma unroll
    for (int st = 0; st < 16; ++st) {
        // issue loads for step st+2 (stay in flight across barriers)
        float4 ya0, ya1; us8_t yb0, yb1;
        if (st < 14) {
            const float* ga = aSrc + (st + 2) * 32;
            ya0 = *(const float4*)(ga);
            ya1 = *(const float4*)(ga + 4);
            const unsigned short* gb = bSrc + (st + 2) * 32;
            yb0 = *(const us8_t*)(gb);
            yb1 = *(const us8_t*)(gb + 8);
        }
        // frag reads from current tile
        us8_t af[4], bf[4];
#pragma unroll
        for (int mf = 0; mf < 4; ++mf) af[mf] = *(const us8_t*)(As + aRd[mf]);
#pragma unroll
        for (int nf = 0; nf < 4; ++nf) bf[nf] = *(const us8_t*)(Bs + bRd[nf]);
        asm volatile("s_waitcnt lgkmcnt(0)" ::: "memory");
        __builtin_amdgcn_s_barrier();          // all reads done -> safe overwrite
        if (st < 15) {
            *(us8_t*)(As + aOff) = pack8c(xa0, xa1);
            *(us8_t*)(Bs + bOff) = xb0;
            *(us8_t*)(Bs + bOff + 8) = xb1;
        }
#pragma unroll
        for (int mf = 0; mf < 4; ++mf)
#pragma unroll
            for (int nf = 0; nf < 4; ++nf)
                acc[mf][nf] = __builtin_amdgcn_mfma_f32_16x16x32_bf16(
                    __builtin_bit_cast(bf16x8, af[mf]),
                    __builtin_bit_cast(bf16x8, bf[nf]), acc[mf][nf], 0, 0, 0);
        asm volatile("s_waitcnt lgkmcnt(0)" ::: "memory");
        __builtin_amdgcn_s_barrier();          // next tile ready
        if (st < 14) { xa0 = ya0; xa1 = ya1; xb0 = yb0; xb1 = yb1; }
    }

    // epilogue: p(s) = sum_n Vw[n] * tanh(C + qs[n]); reduce n over l15 lanes
#pragma unroll
    for (int mf = 0; mf < 4; ++mf)
#pragma unroll
        for (int r = 0; r < 4; ++r) {
            float p = 0.0f;
#pragma unroll
            for (int nf = 0; nf < 4; ++nf)
                p += vw[nf] * fast_tanh(acc[mf][nf][r] + qv[nf]);
            p += __shfl_xor(p, 1, 64);
            p += __shfl_xor(p, 2, 64);
            p += __shfl_xor(p, 4, 64);
            p += __shfl_xor(p, 8, 64);
            if (l15 == 0) pbuf[wn][wm * 64 + mf * 16 + lq * 4 + r] = p;
        }
    __syncthreads();
    if (tid < 128) {
        part[nh * (BB * SS) + b * SS + s0 + tid] =
            pbuf[0][tid] + pbuf[1][tid] + pbuf[2][tid] + pbuf[3][tid];
    }
}

// ---------------------------------------------------------------------------
// k_context (softmax fused): redundant row-denominator per chunk block,
// attn slice write, context accumulation. grid 1024 = b(64) x chunk(16);
// 256 threads, thread owns h-pair (2t, 2t+1).
// ---------------------------------------------------------------------------
__global__ __launch_bounds__(256)
void k_context(const float* __restrict__ enc, const float* __restrict__ part,
               const float* __restrict__ gate, const unsigned char* __restrict__ mask,
               float* __restrict__ attn, float* __restrict__ ctx) {
    int b = blockIdx.x >> 4, chunk = blockIdx.x & 15;
    int s0 = chunk * 64, t = threadIdx.x;
    int w = t >> 6, ln = t & 63;
    float sum = 0.0f;
#pragma unroll
    for (int j = 0; j < 4; ++j) {
        int s = j * 256 + t;
        float raw = part[b * SS + s] + part[BB * SS + b * SS + s];
        float v = mask[b * SS + s] ? -1e30f : raw * gate[b * SS + s];
        sum += __expf(v);
    }
#pragma unroll
    for (int off = 1; off < 64; off <<= 1) sum += __shfl_xor(sum, off, 64);
    __shared__ float sl[4];
    if (ln == 0) sl[w] = sum;
    __syncthreads();
    float inv = 1.0f / (sl[0] + sl[1] + sl[2] + sl[3]);

    __shared__ float aw[64];
    if (t < 64) {
        int s = s0 + t;
        float raw = part[b * SS + s] + part[BB * SS + b * SS + s];
        float v = mask[b * SS + s] ? -1e30f : raw * gate[b * SS + s];
        float a = __expf(v) * inv;
        aw[t] = a;
        attn[b * SS + s] = a;
    }
    __syncthreads();

    const float* eb = enc + ((size_t)(b * SS + s0)) * HH + 2 * t;
    float a0 = 0.f, a1 = 0.f;
#pragma unroll 4
    for (int s = 0; s < 64; ++s) {
        float2 u = *(const float2*)(eb + (size_t)s * HH);
        a0 += aw[s] * u.x;
        a1 += aw[s] * u.y;
    }
    atomicAdd(&ctx[b * HH + 2 * t], a0);
    atomicAdd(&ctx[b * HH + 2 * t + 1], a1);
}

// ---------------------------------------------------------------------------
// k_build: lstm_in_bf16 = [emb | ctx], h_bf16
// ---------------------------------------------------------------------------
__global__ __launch_bounds__(256)
void k_build(const int* __restrict__ tok, const float* __restrict__ embt,
             const float* __restrict__ ctx, const float* __restrict__ hidden,
             unsigned short* __restrict__ li16, unsigned short* __restrict__ h16v) {
    int b = blockIdx.x, t = threadIdx.x;
    const float* er = embt + (size_t)tok[b] * EE;
    for (int i = 2 * t; i < HH; i += 512) {
        *(unsigned int*)(li16 + b * 1024 + i) = cvtpk(er[i], er[i + 1]);
        *(unsigned int*)(li16 + b * 1024 + 512 + i) = cvtpk(ctx[b * HH + i], ctx[b * HH + i + 1]);
        *(unsigned int*)(h16v + b * HH + i) = cvtpk(hidden[b * HH + i], hidden[b * HH + i + 1]);
    }
}

// ---------------------------------------------------------------------------
// k_gates: gpart[ksl] = lstm_in @ W_ih^T + h @ W_hh^T  (K-slice partials)
// grid 64 = 16 n-tiles(128) x 4 k-slices(384).
// ---------------------------------------------------------------------------
__global__ __launch_bounds__(256)
void k_gates(const unsigned short* __restrict__ li16, const unsigned short* __restrict__ h16v,
             const float* __restrict__ Wih, const float* __restrict__ Whh,
             float* __restrict__ gpart) {
    int nt = blockIdx.x >> 2, ksl = blockIdx.x & 3;
    int wave = threadIdx.x >> 6, lane = threadIdx.x & 63;
    int l15 = lane & 15, lq = lane >> 4, k0 = lq * 8;
    int n0w = nt * 128 + wave * 32;
    f32x4 acc[4][2];
#pragma unroll
    for (int mf = 0; mf < 4; ++mf)
#pragma unroll
        for (int nf = 0; nf < 2; ++nf) acc[mf][nf] = (f32x4){0.f, 0.f, 0.f, 0.f};

    for (int ks = 0; ks < 12; ++ks) {
        int kg = ksl * 384 + ks * 32;
        us8_t af[4];
        if (kg < 1024) {
#pragma unroll
            for (int mf = 0; mf < 4; ++mf)
                af[mf] = *(const us8_t*)(li16 + (mf * 16 + l15) * 1024 + kg + k0);
        } else {
#pragma unroll
            for (int mf = 0; mf < 4; ++mf)
                af[mf] = *(const us8_t*)(h16v + (mf * 16 + l15) * 512 + (kg - 1024) + k0);
        }
#pragma unroll
        for (int nf = 0; nf < 2; ++nf) {
            int n = n0w + nf * 16 + l15;
            us8_t bu;
            if (kg < 1024) {
                const float* wr = Wih + (size_t)n * 1024 + kg + k0;
                bu = pack8c(*(const float4*)wr, *(const float4*)(wr + 4));
            } else {
                const float* wr = Whh + (size_t)n * 512 + (kg - 1024) + k0;
                bu = pack8c(*(const float4*)wr, *(const float4*)(wr + 4));
            }
#pragma unroll
            for (int mf = 0; mf < 4; ++mf)
                acc[mf][nf] = __builtin_amdgcn_mfma_f32_16x16x32_bf16(
                    __builtin_bit_cast(bf16x8, af[mf]),
                    __builtin_bit_cast(bf16x8, bu), acc[mf][nf], 0, 0, 0);
        }
    }
#pragma unroll
    for (int mf = 0; mf < 4; ++mf)
#pragma unroll
        for (int nf = 0; nf < 2; ++nf)
#pragma unroll
            for (int r = 0; r < 4; ++r) {
                int row = mf * 16 + lq * 4 + r;
                int n = n0w + nf * 16 + l15;
                gpart[ksl * (BB * 2048) + row * 2048 + n] = acc[mf][nf][r];
            }
}

// ---------------------------------------------------------------------------
// k_lstm: sum K-slice partials + biases, pointwise cell update
// ---------------------------------------------------------------------------
__global__ __launch_bounds__(512)
void k_lstm(const float* __restrict__ gpart, const float* __restrict__ bih,
            const float* __restrict__ bhh, const float* __restrict__ cell,
            float* __restrict__ oh, float* __restrict__ oc,
            unsigned short* __restrict__ h116) {
    int b = blockIdx.x, t = threadIdx.x;
    float gi = bih[t] + bhh[t];
    float gf = bih[512 + t] + bhh[512 + t];
    float gg = bih[1024 + t] + bhh[1024 + t];
    float go = bih[1536 + t] + bhh[1536 + t];
#pragma unroll
    for (int ksl = 0; ksl < 4; ++ksl) {
        const float* gp = gpart + ksl * (BB * 2048) + b * 2048;
        gi += gp[t];
        gf += gp[512 + t];
        gg += gp[1024 + t];
        go += gp[1536 + t];
    }
    float c0 = cell[b * HH + t];
    float c1 = sigmf(gf) * c0 + sigmf(gi) * fast_tanh(gg);
    float h1 = sigmf(go) * fast_tanh(c1);
    oh[b * HH + t] = h1;
    oc[b * HH + t] = c1;
    h116[b * HH + t] = (unsigned short)(cvtpk(h1, h1) & 0xffffu);
}

// ---------------------------------------------------------------------------
// k_pred: pred = h1 @ W_out^T + b_out  (M=64, N=32000, K=512)
// ---------------------------------------------------------------------------
__global__ __launch_bounds__(512)
void k_pred(const unsigned short* __restrict__ h116, const float* __restrict__ Wout,
            const float* __restrict__ bout, float* __restrict__ pred) {
    int wave = threadIdx.x >> 6, lane = threadIdx.x & 63;
    int l15 = lane & 15, lq = lane >> 4, k0 = lq * 8;
    int n = blockIdx.x * 128 + wave * 16 + l15;
    f32x4 acc[4];
#pragma unroll
    for (int mf = 0; mf < 4; ++mf) acc[mf] = (f32x4){0.f, 0.f, 0.f, 0.f};
    const float* wr = Wout + (size_t)n * HH;
#pragma unroll 4
    for (int ks = 0; ks < 16; ++ks) {
        float4 x = *(const float4*)(wr + ks * 32 + k0);
        float4 y = *(const float4*)(wr + ks * 32 + k0 + 4);
        us8_t bu = pack8c(x, y);
#pragma unroll
        for (int mf = 0; mf < 4; ++mf) {
            us8_t au = *(const us8_t*)(h116 + (mf * 16 + l15) * 512 + ks * 32 + k0);
            acc[mf] = __builtin_amdgcn_mfma_f32_16x16x32_bf16(
                __builtin_bit_cast(bf16x8, au),
                __builtin_bit_cast(bf16x8, bu), acc[mf], 0, 0, 0);
        }
    }
    float bo = bout[n];
#pragma unroll
    for (int mf = 0; mf < 4; ++mf)
#pragma unroll
        for (int r = 0; r < 4; ++r) {
            int row = mf * 16 + lq * 4 + r;
            pred[(size_t)row * VV + n] = acc[mf][r] + bo;
        }
}

// ---------------------------------------------------------------------------
extern "C" void kernel_launch(void* const* d_in, const int* in_sizes, int n_in,
                              void* d_out, int out_size, void* d_ws, size_t ws_size,
                              hipStream_t stream) {
    const int* tok = (const int*)d_in[0];
    const float* hidden = (const float*)d_in[1];
    const float* cell = (const float*)d_in[2];
    const float* enc = (const float*)d_in[3];
    const float* pos = (const float*)d_in[4];
    const unsigned char* mask = (const unsigned char*)d_in[5];
    const float* embt = (const float*)d_in[6];
    const float* Ws = (const float*)d_in[7];
    const float* Wh = (const float*)d_in[8];
    const float* Vw = (const float*)d_in[9];
    const float* Wp = (const float*)d_in[10];
    const float* bp = (const float*)d_in[11];
    const float* Wih = (const float*)d_in[12];
    const float* Whh = (const float*)d_in[13];
    const float* bih = (const float*)d_in[14];
    const float* bhh = (const float*)d_in[15];
    const float* Wout = (const float*)d_in[16];
    const float* bout = (const float*)d_in[17];

    float* out = (float*)d_out;
    float* pred = out;                  // 64*32000
    float* out_h = out + 2048000;       // 64*512
    float* out_c = out + 2080768;       // 64*512
    float* attn = out + 2113536;        // 64*1024

    char* wsb = (char*)d_ws;
    unsigned short* wh16 = (unsigned short*)(wsb);                 // 512KB
    float* qs = (float*)(wsb + (512 << 10));                       // 128KB
    float* gate = (float*)(wsb + (640 << 10));                     // 256KB
    float* part = (float*)(wsb + (896 << 10));                     // 512KB
    float* ctx = (float*)(wsb + (1408 << 10));                     // 128KB
    unsigned short* li16 = (unsigned short*)(wsb + (1536 << 10));  // 128KB
    unsigned short* h16v = (unsigned short*)(wsb + (1664 << 10));  // 64KB
    float* gpart = (float*)(wsb + (1728 << 10));                   // 2MB
    unsigned short* h116 = (unsigned short*)(wsb + (3776 << 10));  // 64KB

    hipLaunchKernelGGL(k_prep, dim3(360), dim3(256), 0, stream,
                       hidden, Ws, Wh, pos, Wp, bp, wh16, qs, gate, ctx);
    hipLaunchKernelGGL(k_scores, dim3(1024), dim3(512), 0, stream,
                       enc, wh16, qs, Vw, part);
    hipLaunchKernelGGL(k_context, dim3(1024), dim3(256), 0, stream,
                       enc, part, gate, mask, attn, ctx);
    hipLaunchKernelGGL(k_build, dim3(64), dim3(256), 0, stream,
                       tok, embt, ctx, hidden, li16, h16v);
    hipLaunchKernelGGL(k_gates, dim3(64), dim3(256), 0, stream, li16, h16v, Wih, Whh, gpart);
    hipLaunchKernelGGL(k_lstm, dim3(64), dim3(512), 0, stream,
                       gpart, bih, bhh, cell, out_h, out_c, h116);
    hipLaunchKernelGGL(k_pred, dim3(250), dim3(512), 0, stream, h116, Wout, bout, pred);
}